// Round 6
// baseline (469.735 us; speedup 1.0000x reference)
//
#include <hip/hip_runtime.h>
#include <hip/hip_bf16.h>
#include <stdint.h>

#define T_SEQ 1024
#define DMODEL 3584
#define KVDIM 512
#define NQH 28
#define NKVH 4
#define NREP 7
#define HD 128
#define NTOT 4608          // DMODEL + 2*KVDIM
#define BATCH 2
#define MROWS 2048         // BATCH * T_SEQ
#define KMASK (-3.3895314e38f)

typedef __attribute__((ext_vector_type(8))) short short8;
typedef __attribute__((ext_vector_type(4))) float f32x4;

#define SB()       asm volatile("s_barrier" ::: "memory")
#define WAIT_VM0() asm volatile("s_waitcnt vmcnt(0)" ::: "memory")

__device__ __forceinline__ short8 ld_s8(const __hip_bfloat16* p) {
    return *reinterpret_cast<const short8*>(p);
}

__device__ __forceinline__ f32x4 mfma16(short8 a, short8 b, f32x4 c) {
    return __builtin_amdgcn_mfma_f32_16x16x32_bf16(a, b, c, 0, 0, 0);
}

__device__ __forceinline__ void gload_lds16(const __hip_bfloat16* g, __hip_bfloat16* l) {
    __builtin_amdgcn_global_load_lds(
        (const __attribute__((address_space(1))) unsigned int*)g,
        (__attribute__((address_space(3))) unsigned int*)l,
        16, 0, 0);
}

// ---------------- segment scan: position ids + left pads ----------------
__global__ void scan_kernel(const int* __restrict__ seg, int* __restrict__ pos_ids,
                            int* __restrict__ left_pads) {
    int b = blockIdx.x;
    int t = threadIdx.x;
    __shared__ int cum[T_SEQ];
    __shared__ int lp;
    if (t == 0) lp = 0;
    cum[t] = (seg[b * T_SEQ + t] != 0) ? 1 : 0;
    __syncthreads();
    for (int off = 1; off < T_SEQ; off <<= 1) {
        int add = (t >= off) ? cum[t - off] : 0;
        __syncthreads();
        cum[t] += add;
        __syncthreads();
    }
    pos_ids[b * T_SEQ + t] = cum[t] - 1;
    if (cum[t] == 0) atomicAdd(&lp, 1);
    __syncthreads();
    if (t == 0) left_pads[b] = lp;
}

// ---------------- fp32 -> bf16 elementwise ----------------
__global__ void convert_bf16(const float* __restrict__ x, __hip_bfloat16* __restrict__ xb, int n) {
    int i = (blockIdx.x * blockDim.x + threadIdx.x) * 4;
    if (i >= n) return;
    float4 v = *reinterpret_cast<const float4*>(x + i);
    union { __hip_bfloat16 h[4]; uint2 u; } o;
    o.h[0] = __float2bfloat16(v.x);
    o.h[1] = __float2bfloat16(v.y);
    o.h[2] = __float2bfloat16(v.z);
    o.h[3] = __float2bfloat16(v.w);
    *reinterpret_cast<uint2*>(xb + i) = o.u;
}

// ---------------- transpose + convert: W (KxN fp32) -> WT (NxK bf16) ----------------
__global__ void transpose_convert(const float* __restrict__ W, __hip_bfloat16* __restrict__ WT,
                                  int K, int N) {
    __shared__ float tile[32][33];
    int n0 = blockIdx.x * 32, k0 = blockIdx.y * 32;
    int tx = threadIdx.x, ty = threadIdx.y;   // 32 x 8
#pragma unroll
    for (int j = 0; j < 4; j++)
        tile[ty + j * 8][tx] = W[(size_t)(k0 + ty + j * 8) * N + n0 + tx];
    __syncthreads();
#pragma unroll
    for (int j = 0; j < 4; j++)
        WT[(size_t)(n0 + ty + j * 8) * K + k0 + tx] = __float2bfloat16(tile[tx][ty + j * 8]);
}

// ---------------- bf16 transpose for V: qkv v-section -> vbT [B][512][1024] ----------------
__global__ void transpose_v(const __hip_bfloat16* __restrict__ qkv, __hip_bfloat16* __restrict__ vbT) {
    __shared__ __hip_bfloat16 tile[32][33];
    int c0 = blockIdx.x * 32;   // v col 0..511
    int s0 = blockIdx.y * 32;   // seq within batch
    int b = blockIdx.z;
    int tx = threadIdx.x, ty = threadIdx.y;   // 32 x 8
#pragma unroll
    for (int j = 0; j < 4; j++)
        tile[ty + j * 8][tx] = qkv[(size_t)(b * T_SEQ + s0 + ty + j * 8) * NTOT + DMODEL + KVDIM + c0 + tx];
    __syncthreads();
#pragma unroll
    for (int j = 0; j < 4; j++)
        vbT[((size_t)b * KVDIM + c0 + ty + j * 8) * T_SEQ + s0 + tx] = tile[tx][ty + j * 8];
}

// ---------------- RoPE in-place; 64 sin/cos staged in LDS per row ----------------
__global__ void rope_kernel(__hip_bfloat16* __restrict__ qkv, const int* __restrict__ pos_ids) {
    int row = blockIdx.x;              // 0..2047
    int tid = threadIdx.x;             // 256
    __shared__ float sc[2][64];
    float fpos = (float)pos_ids[row];
    if (tid < 64) {
        float freq = exp2f((float)tid * (-0.31143076632024816f));
        float ang = fpos * freq;
        sc[0][tid] = sinf(ang);
        sc[1][tid] = cosf(ang);
    }
    __syncthreads();
    __hip_bfloat16* rp = qkv + (size_t)row * NTOT;
    for (int p = tid; p < 32 * 64; p += 256) {
        int hh = p >> 6;
        int j = p & 63;
        int cb = (hh < NQH) ? hh * HD : DMODEL + (hh - NQH) * HD;
        float s = sc[0][j], c = sc[1][j];
        float x1 = __bfloat162float(rp[cb + j]);
        float x2 = __bfloat162float(rp[cb + j + 64]);
        rp[cb + j] = __float2bfloat16(x1 * c - x2 * s);
        rp[cb + j + 64] = __float2bfloat16(x2 * c + x1 * s);
    }
}

// ---------------- 256x256x64 8-phase bf16 GEMM (T1+T2+T3/T4+T5) ----------------
// C = A * BT^T. A: MxK bf16 row-major; BT: NxK bf16 row-major. 512 threads,
// 8 waves (2M x 4N), per-wave C = 128x64. LDS 128KB double-buffered; XOR-swizzled
// (pre-swizzled global src, rule #21). Raw s_barrier phases; one vmcnt(0)/window
// with ~3 phases of issue-ahead cover. MODE 0: bf16 out + qkv bias; MODE 1: fp32.
template <int MODE>
__global__ __launch_bounds__(512, 2) void gemm256(
    const __hip_bfloat16* __restrict__ A, const __hip_bfloat16* __restrict__ BT,
    int M, int N, int K, int nbx,
    const float* __restrict__ bq, const float* __restrict__ bk, const float* __restrict__ bv,
    __hip_bfloat16* __restrict__ Cb, float* __restrict__ Cf) {
    __shared__ __hip_bfloat16 As[2][256 * 64];   // 64KB
    __shared__ __hip_bfloat16 Bs[2][256 * 64];   // 64KB
    int tid = threadIdx.x;
    int wv = tid >> 6, lane = tid & 63;
    int wr = wv >> 2, wc = wv & 3;
    int r16 = lane & 15, g4 = lane >> 4;
    // T1: XCD swizzle (gridDim.x divisible by 8); by = XCD -> A-panel L2-resident
    int nwg = gridDim.x;
    int sb = ((int)blockIdx.x & 7) * (nwg >> 3) + ((int)blockIdx.x >> 3);
    int bx = sb % nbx, by = sb / nbx;
    int bm = by * 256, bn = bx * 256;
    int nt = K >> 6;

    // staging: per-lane pre-swizzled global source, linear LDS dest
    int lrow = lane >> 3;                    // 0..7 rows within 1KB chunk
    int srcoff = ((lane & 7) * 8) ^ (lrow * 8);   // elem offset within 64-elem k row

    auto stageA = [&](int buf, int t) {
        const __hip_bfloat16* src = A + (size_t)t * 64 + srcoff;
#pragma unroll
        for (int h = 0; h < 2; h++)
#pragma unroll
            for (int i = 0; i < 2; i++) {
                int r0 = h * 128 + wv * 16 + i * 8;
                gload_lds16(src + (size_t)(bm + r0 + lrow) * K, &As[buf][r0 * 64]);
            }
    };
    auto stageB = [&](int buf, int t) {
        const __hip_bfloat16* src = BT + (size_t)t * 64 + srcoff;
#pragma unroll
        for (int h = 0; h < 2; h++)
#pragma unroll
            for (int i = 0; i < 2; i++) {
                int r0 = h * 128 + wv * 16 + i * 8;
                gload_lds16(src + (size_t)(bn + r0 + lrow) * K, &Bs[buf][r0 * 64]);
            }
    };
    int swz = (r16 & 7) << 3;

    f32x4 acc[8][4] = {};
    stageA(0, 0);
    stageB(0, 0);

    for (int w = 0; w < nt; w++) {
        int buf = w & 1;
        WAIT_VM0();                 // tile w resident (all waves after barrier)
        SB();
        short8 aF[4][2], bF0[2][2], bF1[2][2];
        // ---- p0: read aF(mq=0) + bF0; stage A(w+1); MFMA quad (0,0) ----
#pragma unroll
        for (int mi = 0; mi < 4; mi++)
#pragma unroll
            for (int ks = 0; ks < 2; ks++) {
                int row = wr * 128 + mi * 16 + r16;
                aF[mi][ks] = ld_s8(&As[buf][row * 64 + ((ks * 32 + g4 * 8) ^ swz)]);
            }
#pragma unroll
        for (int ni = 0; ni < 2; ni++)
#pragma unroll
            for (int ks = 0; ks < 2; ks++) {
                int row = wc * 64 + ni * 16 + r16;
                bF0[ni][ks] = ld_s8(&Bs[buf][row * 64 + ((ks * 32 + g4 * 8) ^ swz)]);
            }
        if (w + 1 < nt) stageA(buf ^ 1, w + 1);
        SB();
        __builtin_amdgcn_s_setprio(1);
#pragma unroll
        for (int mi = 0; mi < 4; mi++)
#pragma unroll
            for (int ni = 0; ni < 2; ni++) {
                acc[mi][ni] = mfma16(aF[mi][0], bF0[ni][0], acc[mi][ni]);
                acc[mi][ni] = mfma16(aF[mi][1], bF0[ni][1], acc[mi][ni]);
            }
        __builtin_amdgcn_s_setprio(0);
        SB();
        // ---- p1: read bF1; stage B(w+1); MFMA quad (0,1) ----
#pragma unroll
        for (int ni = 0; ni < 2; ni++)
#pragma unroll
            for (int ks = 0; ks < 2; ks++) {
                int row = wc * 64 + (2 + ni) * 16 + r16;
                bF1[ni][ks] = ld_s8(&Bs[buf][row * 64 + ((ks * 32 + g4 * 8) ^ swz)]);
            }
        if (w + 1 < nt) stageB(buf ^ 1, w + 1);
        SB();
        __builtin_amdgcn_s_setprio(1);
#pragma unroll
        for (int mi = 0; mi < 4; mi++)
#pragma unroll
            for (int ni = 0; ni < 2; ni++) {
                acc[mi][2 + ni] = mfma16(aF[mi][0], bF1[ni][0], acc[mi][2 + ni]);
                acc[mi][2 + ni] = mfma16(aF[mi][1], bF1[ni][1], acc[mi][2 + ni]);
            }
        __builtin_amdgcn_s_setprio(0);
        SB();
        // ---- p2: read aF(mq=1); MFMA quad (1,0) ----
#pragma unroll
        for (int mi = 0; mi < 4; mi++)
#pragma unroll
            for (int ks = 0; ks < 2; ks++) {
                int row = wr * 128 + 64 + mi * 16 + r16;
                aF[mi][ks] = ld_s8(&As[buf][row * 64 + ((ks * 32 + g4 * 8) ^ swz)]);
            }
        SB();
        __builtin_amdgcn_s_setprio(1);
#pragma unroll
        for (int mi = 0; mi < 4; mi++)
#pragma unroll
            for (int ni = 0; ni < 2; ni++) {
                acc[4 + mi][ni] = mfma16(aF[mi][0], bF0[ni][0], acc[4 + mi][ni]);
                acc[4 + mi][ni] = mfma16(aF[mi][1], bF0[ni][1], acc[4 + mi][ni]);
            }
        __builtin_amdgcn_s_setprio(0);
        SB();
        // ---- p3: MFMA quad (1,1) (all frags in regs) ----
        __builtin_amdgcn_s_setprio(1);
#pragma unroll
        for (int mi = 0; mi < 4; mi++)
#pragma unroll
            for (int ni = 0; ni < 2; ni++) {
                acc[4 + mi][2 + ni] = mfma16(aF[mi][0], bF1[ni][0], acc[4 + mi][2 + ni]);
                acc[4 + mi][2 + ni] = mfma16(aF[mi][1], bF1[ni][1], acc[4 + mi][2 + ni]);
            }
        __builtin_amdgcn_s_setprio(0);
    }
    // epilogue: C/D layout col=lane&15, row=(lane>>4)*4+reg
#pragma unroll
    for (int m = 0; m < 8; m++) {
#pragma unroll
        for (int n = 0; n < 4; n++) {
            int row0 = bm + wr * 128 + m * 16 + g4 * 4;
            int col = bn + wc * 64 + n * 16 + r16;
            float badd = 0.0f;
            if (MODE == 0)
                badd = (col < DMODEL) ? bq[col]
                       : (col < DMODEL + KVDIM ? bk[col - DMODEL] : bv[col - DMODEL - KVDIM]);
#pragma unroll
            for (int reg = 0; reg < 4; reg++) {
                float v = acc[m][n][reg] + badd;
                if (MODE == 0)
                    Cb[(size_t)(row0 + reg) * N + col] = __float2bfloat16(v);
                else
                    Cf[(size_t)(row0 + reg) * N + col] = v;
            }
        }
    }
}

// ---------------- flash attention: 7 waves/block (one per GQA q-head) ----------------
__global__ __launch_bounds__(448, 4) void attn_kernel(
    const __hip_bfloat16* __restrict__ qkv, const __hip_bfloat16* __restrict__ vbT,
    const int* __restrict__ seg, const int* __restrict__ left_pads,
    __hip_bfloat16* __restrict__ attn_out) {
    int qt_raw = blockIdx.x;
    int kvh = blockIdx.y;
    int b = blockIdx.z;
    int qt = (b == 1) ? 63 - qt_raw : qt_raw;
    int tid = threadIdx.x;
    int w = tid >> 6;
    int lane = tid & 63;
    int r = lane & 15, g = lane >> 4;
    int h = kvh * NREP + w;
    int start = left_pads[b];
    const float scale = 0.08838834764831845f;

    __shared__ __hip_bfloat16 Kt[2][64 * 128];
    __shared__ __hip_bfloat16 Vt[2][128 * 64];
    __shared__ __hip_bfloat16 Ps[NREP][16 * 64];

    const __hip_bfloat16* Qp = qkv + (size_t)(b * T_SEQ + qt * 16 + r) * NTOT + h * HD;
    short8 qf[4];
#pragma unroll
    for (int kc = 0; kc < 4; kc++) qf[kc] = ld_s8(Qp + kc * 32 + g * 8);

    int qrow = qt * 16 + r;
    int segq = seg[b * T_SEQ + qrow];
    int qpos = qrow - start;

    float m_run = -__builtin_inff();
    float l_part = 0.0f;
    f32x4 acc[8] = {};

    const __hip_bfloat16* Kg = qkv + (size_t)(b * T_SEQ) * NTOT + DMODEL + kvh * HD;
    const __hip_bfloat16* Vg = vbT + ((size_t)b * KVDIM + kvh * HD) * T_SEQ;
    int nt = qt / 4 + 1;

    auto stage = [&](int buf, int t) {
        int s0 = t * 64;
        for (int i = w; i < 16; i += NREP) {
            int slot = i * 64 + lane;
            int row = slot >> 4;
            int c = ((slot & 15) << 4) ^ ((row & 7) << 4);
            gload_lds16(Kg + (size_t)(s0 + row) * NTOT + (c >> 1), &Kt[buf][i * 512]);
        }
        for (int i = w; i < 16; i += NREP) {
            int slot = i * 64 + lane;
            int d = slot >> 3;
            int c = ((slot & 7) << 4) ^ ((d & 7) << 4);
            gload_lds16(Vg + (size_t)d * T_SEQ + s0 + (c >> 1), &Vt[buf][i * 512]);
        }
    };

    stage(0, 0);
    __syncthreads();
    int buf = 0;
    for (int t = 0; t < nt; t++) {
        if (t + 1 < nt) stage(buf ^ 1, t + 1);
        int s0 = t * 64;
        f32x4 sacc[4] = {};
#pragma unroll
        for (int n = 0; n < 4; n++) {
#pragma unroll
            for (int kc = 0; kc < 4; kc++) {
                int col = (kc * 32 + g * 8) ^ ((r & 7) << 3);
                short8 kf = ld_s8(&Kt[buf][(n * 16 + r) * 128 + col]);
                sacc[n] = mfma16(kf, qf[kc], sacc[n]);
            }
        }
        float p[16];
        float mt = -__builtin_inff();
#pragma unroll
        for (int n = 0; n < 4; n++)
#pragma unroll
            for (int reg = 0; reg < 4; reg++) {
                int kv = s0 + n * 16 + g * 4 + reg;
                float val = sacc[n][reg] * scale;
                bool ok = (kv - start <= qpos) && (((kv >= start) ? 1 : 0) == segq);
                val = ok ? val : KMASK;
                p[n * 4 + reg] = val;
                mt = fmaxf(mt, val);
            }
        mt = fmaxf(mt, __shfl_xor(mt, 16, 64));
        mt = fmaxf(mt, __shfl_xor(mt, 32, 64));
        if (!__all(mt <= m_run + 8.0f)) {
            float mn = fmaxf(m_run, mt);
            float fac = __expf(m_run - mn);
            m_run = mn;
            l_part *= fac;
            float facr[4];
#pragma unroll
            for (int reg = 0; reg < 4; reg++) facr[reg] = __shfl(fac, g * 4 + reg, 64);
#pragma unroll
            for (int h7 = 0; h7 < 8; h7++)
#pragma unroll
                for (int reg = 0; reg < 4; reg++)
                    acc[h7][reg] *= facr[reg];
        }
#pragma unroll
        for (int i = 0; i < 16; i++) {
            p[i] = __expf(p[i] - m_run);
            l_part += p[i];
        }
#pragma unroll
        for (int n = 0; n < 4; n++) {
            union { __hip_bfloat16 h[4]; uint2 u; } pk;
#pragma unroll
            for (int reg = 0; reg < 4; reg++) pk.h[reg] = __float2bfloat16(p[n * 4 + reg]);
            int col = (n * 16 + g * 4) ^ ((r & 7) << 3);
            *reinterpret_cast<uint2*>(&Ps[w][r * 64 + col]) = pk.u;
        }
#pragma unroll
        for (int kc = 0; kc < 2; kc++) {
            int colp = (kc * 32 + g * 8) ^ ((r & 7) << 3);
            short8 a_pv = ld_s8(&Ps[w][r * 64 + colp]);
#pragma unroll
            for (int h7 = 0; h7 < 8; h7++) {
                int d = h7 * 16 + r;
                int colv = (kc * 32 + g * 8) ^ ((r & 7) << 3);
                short8 vf = ld_s8(&Vt[buf][d * 64 + colv]);
                acc[h7] = mfma16(a_pv, vf, acc[h7]);
            }
        }
        __syncthreads();
        buf ^= 1;
    }
    l_part += __shfl_xor(l_part, 16, 64);
    l_part += __shfl_xor(l_part, 32, 64);
    float invl[4];
#pragma unroll
    for (int reg = 0; reg < 4; reg++) invl[reg] = 1.0f / __shfl(l_part, g * 4 + reg, 64);
#pragma unroll
    for (int h7 = 0; h7 < 8; h7++)
#pragma unroll
        for (int reg = 0; reg < 4; reg++)
            attn_out[(size_t)(b * T_SEQ + qt * 16 + g * 4 + reg) * DMODEL + h * HD + h7 * 16 + r] =
                __float2bfloat16(acc[h7][reg] * invl[reg]);
}

extern "C" void kernel_launch(void* const* d_in, const int* in_sizes, int n_in,
                              void* d_out, int out_size, void* d_ws, size_t ws_size,
                              hipStream_t stream) {
    const float* x = (const float*)d_in[0];
    const int* seg = (const int*)d_in[1];
    const float* Wq = (const float*)d_in[4];
    const float* bq = (const float*)d_in[5];
    const float* Wk = (const float*)d_in[6];
    const float* bk = (const float*)d_in[7];
    const float* Wv = (const float*)d_in[8];
    const float* bv = (const float*)d_in[9];
    const float* Wo = (const float*)d_in[10];
    float* out = (float*)d_out;

    uint8_t* ws = (uint8_t*)d_ws;
    size_t off = 0;
    auto alloc = [&](size_t bytes) -> void* {
        void* p = ws + off;
        off += (bytes + 255) & ~(size_t)255;
        return p;
    };
    int* pos_ids = (int*)alloc(MROWS * sizeof(int));
    int* left_pads = (int*)alloc(16 * sizeof(int));
    __hip_bfloat16* xb = (__hip_bfloat16*)alloc((size_t)MROWS * DMODEL * 2);
    __hip_bfloat16* WqkvT = (__hip_bfloat16*)alloc((size_t)NTOT * DMODEL * 2);
    __hip_bfloat16* WoT = (__hip_bfloat16*)alloc((size_t)DMODEL * DMODEL * 2);
    __hip_bfloat16* qkv = (__hip_bfloat16*)alloc((size_t)MROWS * NTOT * 2);
    __hip_bfloat16* vbT = (__hip_bfloat16*)alloc((size_t)BATCH * KVDIM * T_SEQ * 2);
    __hip_bfloat16* attn = (__hip_bfloat16*)alloc((size_t)MROWS * DMODEL * 2);

    scan_kernel<<<BATCH, T_SEQ, 0, stream>>>(seg, pos_ids, left_pads);
    convert_bf16<<<(MROWS * DMODEL / 4 + 255) / 256, 256, 0, stream>>>(x, xb, MROWS * DMODEL);
    transpose_convert<<<dim3(DMODEL / 32, DMODEL / 32), dim3(32, 8), 0, stream>>>(Wq, WqkvT, DMODEL, DMODEL);
    transpose_convert<<<dim3(KVDIM / 32, DMODEL / 32), dim3(32, 8), 0, stream>>>(
        Wk, WqkvT + (size_t)DMODEL * DMODEL, DMODEL, KVDIM);
    transpose_convert<<<dim3(KVDIM / 32, DMODEL / 32), dim3(32, 8), 0, stream>>>(
        Wv, WqkvT + (size_t)(DMODEL + KVDIM) * DMODEL, DMODEL, KVDIM);
    transpose_convert<<<dim3(DMODEL / 32, DMODEL / 32), dim3(32, 8), 0, stream>>>(Wo, WoT, DMODEL, DMODEL);
    gemm256<0><<<dim3((NTOT / 256) * (MROWS / 256)), 512, 0, stream>>>(
        xb, WqkvT, MROWS, NTOT, DMODEL, NTOT / 256, bq, bk, bv, qkv, nullptr);
    rope_kernel<<<MROWS, 256, 0, stream>>>(qkv, pos_ids);
    transpose_v<<<dim3(KVDIM / 32, T_SEQ / 32, BATCH), dim3(32, 8), 0, stream>>>(qkv, vbT);
    attn_kernel<<<dim3(T_SEQ / 16, NKVH, BATCH), 448, 0, stream>>>(qkv, vbT, seg, left_pads, attn);
    gemm256<1><<<dim3((DMODEL / 256) * (MROWS / 256)), 512, 0, stream>>>(
        attn, WoT, MROWS, DMODEL, DMODEL, DMODEL / 256, nullptr, nullptr, nullptr, nullptr, out);
}

// Round 7
// 407.157 us; speedup vs baseline: 1.1537x; 1.1537x over previous
//
#include <hip/hip_runtime.h>
#include <hip/hip_bf16.h>
#include <stdint.h>

#define T_SEQ 1024
#define DMODEL 3584
#define KVDIM 512
#define NQH 28
#define NKVH 4
#define NREP 7
#define HD 128
#define NTOT 4608          // DMODEL + 2*KVDIM
#define BATCH 2
#define MROWS 2048         // BATCH * T_SEQ
#define KMASK (-3.3895314e38f)

typedef __attribute__((ext_vector_type(8))) short short8;
typedef __attribute__((ext_vector_type(4))) float f32x4;

#define SB()       asm volatile("s_barrier" ::: "memory")
#define WAIT_VM0() asm volatile("s_waitcnt vmcnt(0)" ::: "memory")

__device__ __forceinline__ short8 ld_s8(const __hip_bfloat16* p) {
    return *reinterpret_cast<const short8*>(p);
}

__device__ __forceinline__ f32x4 mfma16(short8 a, short8 b, f32x4 c) {
    return __builtin_amdgcn_mfma_f32_16x16x32_bf16(a, b, c, 0, 0, 0);
}

__device__ __forceinline__ void gload_lds16(const __hip_bfloat16* g, __hip_bfloat16* l) {
    __builtin_amdgcn_global_load_lds(
        (const __attribute__((address_space(1))) unsigned int*)g,
        (__attribute__((address_space(3))) unsigned int*)l,
        16, 0, 0);
}

// ---------------- segment scan: position ids + left pads ----------------
__global__ void scan_kernel(const int* __restrict__ seg, int* __restrict__ pos_ids,
                            int* __restrict__ left_pads) {
    int b = blockIdx.x;
    int t = threadIdx.x;
    __shared__ int cum[T_SEQ];
    __shared__ int lp;
    if (t == 0) lp = 0;
    cum[t] = (seg[b * T_SEQ + t] != 0) ? 1 : 0;
    __syncthreads();
    for (int off = 1; off < T_SEQ; off <<= 1) {
        int add = (t >= off) ? cum[t - off] : 0;
        __syncthreads();
        cum[t] += add;
        __syncthreads();
    }
    pos_ids[b * T_SEQ + t] = cum[t] - 1;
    if (cum[t] == 0) atomicAdd(&lp, 1);
    __syncthreads();
    if (t == 0) left_pads[b] = lp;
}

// ---------------- fp32 -> bf16 elementwise ----------------
__global__ void convert_bf16(const float* __restrict__ x, __hip_bfloat16* __restrict__ xb, int n) {
    int i = (blockIdx.x * blockDim.x + threadIdx.x) * 4;
    if (i >= n) return;
    float4 v = *reinterpret_cast<const float4*>(x + i);
    union { __hip_bfloat16 h[4]; uint2 u; } o;
    o.h[0] = __float2bfloat16(v.x);
    o.h[1] = __float2bfloat16(v.y);
    o.h[2] = __float2bfloat16(v.z);
    o.h[3] = __float2bfloat16(v.w);
    *reinterpret_cast<uint2*>(xb + i) = o.u;
}

// ---------------- transpose + convert: W (KxN fp32) -> WT (NxK bf16) ----------------
__global__ void transpose_convert(const float* __restrict__ W, __hip_bfloat16* __restrict__ WT,
                                  int K, int N) {
    __shared__ float tile[32][33];
    int n0 = blockIdx.x * 32, k0 = blockIdx.y * 32;
    int tx = threadIdx.x, ty = threadIdx.y;   // 32 x 8
#pragma unroll
    for (int j = 0; j < 4; j++)
        tile[ty + j * 8][tx] = W[(size_t)(k0 + ty + j * 8) * N + n0 + tx];
    __syncthreads();
#pragma unroll
    for (int j = 0; j < 4; j++)
        WT[(size_t)(n0 + ty + j * 8) * K + k0 + tx] = __float2bfloat16(tile[tx][ty + j * 8]);
}

// ---------------- bf16 transpose for V: qkv v-section -> vbT [B][512][1024] ----------------
__global__ void transpose_v(const __hip_bfloat16* __restrict__ qkv, __hip_bfloat16* __restrict__ vbT) {
    __shared__ __hip_bfloat16 tile[32][33];
    int c0 = blockIdx.x * 32;   // v col 0..511
    int s0 = blockIdx.y * 32;   // seq within batch
    int b = blockIdx.z;
    int tx = threadIdx.x, ty = threadIdx.y;   // 32 x 8
#pragma unroll
    for (int j = 0; j < 4; j++)
        tile[ty + j * 8][tx] = qkv[(size_t)(b * T_SEQ + s0 + ty + j * 8) * NTOT + DMODEL + KVDIM + c0 + tx];
    __syncthreads();
#pragma unroll
    for (int j = 0; j < 4; j++)
        vbT[((size_t)b * KVDIM + c0 + ty + j * 8) * T_SEQ + s0 + tx] = tile[tx][ty + j * 8];
}

// ---------------- RoPE in-place; 64 sin/cos staged in LDS per row ----------------
__global__ void rope_kernel(__hip_bfloat16* __restrict__ qkv, const int* __restrict__ pos_ids) {
    int row = blockIdx.x;              // 0..2047
    int tid = threadIdx.x;             // 256
    __shared__ float sc[2][64];
    float fpos = (float)pos_ids[row];
    if (tid < 64) {
        float freq = exp2f((float)tid * (-0.31143076632024816f));
        float ang = fpos * freq;
        sc[0][tid] = sinf(ang);
        sc[1][tid] = cosf(ang);
    }
    __syncthreads();
    __hip_bfloat16* rp = qkv + (size_t)row * NTOT;
    for (int p = tid; p < 32 * 64; p += 256) {
        int hh = p >> 6;
        int j = p & 63;
        int cb = (hh < NQH) ? hh * HD : DMODEL + (hh - NQH) * HD;
        float s = sc[0][j], c = sc[1][j];
        float x1 = __bfloat162float(rp[cb + j]);
        float x2 = __bfloat162float(rp[cb + j + 64]);
        rp[cb + j] = __float2bfloat16(x1 * c - x2 * s);
        rp[cb + j + 64] = __float2bfloat16(x2 * c + x1 * s);
    }
}

// ---------------- 128xBN 8-phase bf16 GEMM, exact-fill grid (256 blocks) ----------------
// C = A * BT^T. A: MxK bf16 row-major; BT: NxK bf16 row-major. NW waves, each
// owning 128x32 of C (acc[8][2]). BK=64 double-buffered LDS, XOR-swizzled via
// pre-swizzled global src (rule #21, proven in gemm256 r6: 0 bank conflicts).
// Loads stay in flight across raw s_barriers; one vmcnt(0) drain per K-tile.
// MODE 0: bf16 out + qkv bias; MODE 1: fp32 out.
template <int BN, int NW, int MODE>
__global__ __launch_bounds__(NW * 64, 1) void gemmX(
    const __hip_bfloat16* __restrict__ A, const __hip_bfloat16* __restrict__ BT,
    int M, int N, int K, int nbx,
    const float* __restrict__ bq, const float* __restrict__ bk, const float* __restrict__ bv,
    __hip_bfloat16* __restrict__ Cb, float* __restrict__ Cf) {
    constexpr int BM = 128;
    constexpr int NCHA = BM / 8;     // 8-row 1KB chunks
    constexpr int NCHB = BN / 8;
    __shared__ __hip_bfloat16 As[2][BM * 64];
    __shared__ __hip_bfloat16 Bs[2][BN * 64];
    int tid = threadIdx.x;
    int wv = tid >> 6, lane = tid & 63;
    int r16 = lane & 15, g4 = lane >> 4;
    // T1: bijective XCD swizzle (gridDim.x = 256, multiple of 8)
    int nwg = gridDim.x;
    int sb = ((int)blockIdx.x & 7) * (nwg >> 3) + ((int)blockIdx.x >> 3);
    int bx = sb % nbx, by = sb / nbx;
    int bm = by * BM, bn = bx * BN;
    int nt = K >> 6;

    int lrow = lane >> 3;                          // 0..7 row within chunk
    int srcoff = ((lane & 7) * 8) ^ (lrow * 8);    // pre-swizzled src elem offset

    auto stageA = [&](int buf, int t) {
        const __hip_bfloat16* src = A + (size_t)t * 64 + srcoff;
#pragma unroll
        for (int c = 0; c < NCHA; c += NW) {
            int cc = c + wv;
            if (cc < NCHA)
                gload_lds16(src + (size_t)(bm + cc * 8 + lrow) * K, &As[buf][cc * 512]);
        }
    };
    auto stageB = [&](int buf, int t) {
        const __hip_bfloat16* src = BT + (size_t)t * 64 + srcoff;
#pragma unroll
        for (int c = 0; c < NCHB; c += NW) {
            int cc = c + wv;
            if (cc < NCHB)
                gload_lds16(src + (size_t)(bn + cc * 8 + lrow) * K, &Bs[buf][cc * 512]);
        }
    };
    int swz = (r16 & 7) << 3;

    f32x4 acc[8][2] = {};
    stageA(0, 0);
    stageB(0, 0);

    for (int w = 0; w < nt; w++) {
        int buf = w & 1;
        WAIT_VM0();                 // tile w resident
        SB();
        short8 aLo[4][2], aHi[4][2], bF[2][2];
        // ---- p0: read aLo + bF; issue stage A(w+1); MFMA m-half 0 ----
#pragma unroll
        for (int mi = 0; mi < 4; mi++)
#pragma unroll
            for (int ks = 0; ks < 2; ks++)
                aLo[mi][ks] = ld_s8(&As[buf][(mi * 16 + r16) * 64 + ((ks * 32 + g4 * 8) ^ swz)]);
#pragma unroll
        for (int ni = 0; ni < 2; ni++)
#pragma unroll
            for (int ks = 0; ks < 2; ks++)
                bF[ni][ks] = ld_s8(&Bs[buf][(wv * 32 + ni * 16 + r16) * 64 + ((ks * 32 + g4 * 8) ^ swz)]);
        if (w + 1 < nt) stageA(buf ^ 1, w + 1);
        SB();
        __builtin_amdgcn_s_setprio(1);
#pragma unroll
        for (int mi = 0; mi < 4; mi++)
#pragma unroll
            for (int ni = 0; ni < 2; ni++) {
                acc[mi][ni] = mfma16(aLo[mi][0], bF[ni][0], acc[mi][ni]);
                acc[mi][ni] = mfma16(aLo[mi][1], bF[ni][1], acc[mi][ni]);
            }
        __builtin_amdgcn_s_setprio(0);
        SB();
        // ---- p1: read aHi; issue stage B(w+1); MFMA m-half 1 ----
#pragma unroll
        for (int mi = 0; mi < 4; mi++)
#pragma unroll
            for (int ks = 0; ks < 2; ks++)
                aHi[mi][ks] = ld_s8(&As[buf][((64 + mi * 16 + r16)) * 64 + ((ks * 32 + g4 * 8) ^ swz)]);
        if (w + 1 < nt) stageB(buf ^ 1, w + 1);
        SB();
        __builtin_amdgcn_s_setprio(1);
#pragma unroll
        for (int mi = 0; mi < 4; mi++)
#pragma unroll
            for (int ni = 0; ni < 2; ni++) {
                acc[4 + mi][ni] = mfma16(aHi[mi][0], bF[ni][0], acc[4 + mi][ni]);
                acc[4 + mi][ni] = mfma16(aHi[mi][1], bF[ni][1], acc[4 + mi][ni]);
            }
        __builtin_amdgcn_s_setprio(0);
    }
    // epilogue: C/D layout col=lane&15, row=(lane>>4)*4+reg
#pragma unroll
    for (int m = 0; m < 8; m++) {
#pragma unroll
        for (int n = 0; n < 2; n++) {
            int row0 = bm + m * 16 + g4 * 4;
            int col = bn + wv * 32 + n * 16 + r16;
            float badd = 0.0f;
            if (MODE == 0)
                badd = (col < DMODEL) ? bq[col]
                       : (col < DMODEL + KVDIM ? bk[col - DMODEL] : bv[col - DMODEL - KVDIM]);
#pragma unroll
            for (int reg = 0; reg < 4; reg++) {
                float v = acc[m][n][reg] + badd;
                if (MODE == 0)
                    Cb[(size_t)(row0 + reg) * N + col] = __float2bfloat16(v);
                else
                    Cf[(size_t)(row0 + reg) * N + col] = v;
            }
        }
    }
}

// ---------------- flash attention: 7 waves/block (one per GQA q-head) ----------------
__global__ __launch_bounds__(448, 4) void attn_kernel(
    const __hip_bfloat16* __restrict__ qkv, const __hip_bfloat16* __restrict__ vbT,
    const int* __restrict__ seg, const int* __restrict__ left_pads,
    __hip_bfloat16* __restrict__ attn_out) {
    int qt_raw = blockIdx.x;
    int kvh = blockIdx.y;
    int b = blockIdx.z;
    int qt = (b == 1) ? 63 - qt_raw : qt_raw;
    int tid = threadIdx.x;
    int w = tid >> 6;
    int lane = tid & 63;
    int r = lane & 15, g = lane >> 4;
    int h = kvh * NREP + w;
    int start = left_pads[b];
    const float scale = 0.08838834764831845f;

    __shared__ __hip_bfloat16 Kt[2][64 * 128];
    __shared__ __hip_bfloat16 Vt[2][128 * 64];
    __shared__ __hip_bfloat16 Ps[NREP][16 * 64];

    const __hip_bfloat16* Qp = qkv + (size_t)(b * T_SEQ + qt * 16 + r) * NTOT + h * HD;
    short8 qf[4];
#pragma unroll
    for (int kc = 0; kc < 4; kc++) qf[kc] = ld_s8(Qp + kc * 32 + g * 8);

    int qrow = qt * 16 + r;
    int segq = seg[b * T_SEQ + qrow];
    int qpos = qrow - start;

    float m_run = -__builtin_inff();
    float l_part = 0.0f;
    f32x4 acc[8] = {};

    const __hip_bfloat16* Kg = qkv + (size_t)(b * T_SEQ) * NTOT + DMODEL + kvh * HD;
    const __hip_bfloat16* Vg = vbT + ((size_t)b * KVDIM + kvh * HD) * T_SEQ;
    int nt = qt / 4 + 1;

    auto stage = [&](int buf, int t) {
        int s0 = t * 64;
        for (int i = w; i < 16; i += NREP) {
            int slot = i * 64 + lane;
            int row = slot >> 4;
            int c = ((slot & 15) << 4) ^ ((row & 7) << 4);
            gload_lds16(Kg + (size_t)(s0 + row) * NTOT + (c >> 1), &Kt[buf][i * 512]);
        }
        for (int i = w; i < 16; i += NREP) {
            int slot = i * 64 + lane;
            int d = slot >> 3;
            int c = ((slot & 7) << 4) ^ ((d & 7) << 4);
            gload_lds16(Vg + (size_t)d * T_SEQ + s0 + (c >> 1), &Vt[buf][i * 512]);
        }
    };

    stage(0, 0);
    __syncthreads();
    int buf = 0;
    for (int t = 0; t < nt; t++) {
        if (t + 1 < nt) stage(buf ^ 1, t + 1);
        int s0 = t * 64;
        f32x4 sacc[4] = {};
#pragma unroll
        for (int n = 0; n < 4; n++) {
#pragma unroll
            for (int kc = 0; kc < 4; kc++) {
                int col = (kc * 32 + g * 8) ^ ((r & 7) << 3);
                short8 kf = ld_s8(&Kt[buf][(n * 16 + r) * 128 + col]);
                sacc[n] = mfma16(kf, qf[kc], sacc[n]);
            }
        }
        float p[16];
        float mt = -__builtin_inff();
#pragma unroll
        for (int n = 0; n < 4; n++)
#pragma unroll
            for (int reg = 0; reg < 4; reg++) {
                int kv = s0 + n * 16 + g * 4 + reg;
                float val = sacc[n][reg] * scale;
                bool ok = (kv - start <= qpos) && (((kv >= start) ? 1 : 0) == segq);
                val = ok ? val : KMASK;
                p[n * 4 + reg] = val;
                mt = fmaxf(mt, val);
            }
        mt = fmaxf(mt, __shfl_xor(mt, 16, 64));
        mt = fmaxf(mt, __shfl_xor(mt, 32, 64));
        if (!__all(mt <= m_run + 8.0f)) {
            float mn = fmaxf(m_run, mt);
            float fac = __expf(m_run - mn);
            m_run = mn;
            l_part *= fac;
            float facr[4];
#pragma unroll
            for (int reg = 0; reg < 4; reg++) facr[reg] = __shfl(fac, g * 4 + reg, 64);
#pragma unroll
            for (int h7 = 0; h7 < 8; h7++)
#pragma unroll
                for (int reg = 0; reg < 4; reg++)
                    acc[h7][reg] *= facr[reg];
        }
#pragma unroll
        for (int i = 0; i < 16; i++) {
            p[i] = __expf(p[i] - m_run);
            l_part += p[i];
        }
#pragma unroll
        for (int n = 0; n < 4; n++) {
            union { __hip_bfloat16 h[4]; uint2 u; } pk;
#pragma unroll
            for (int reg = 0; reg < 4; reg++) pk.h[reg] = __float2bfloat16(p[n * 4 + reg]);
            int col = (n * 16 + g * 4) ^ ((r & 7) << 3);
            *reinterpret_cast<uint2*>(&Ps[w][r * 64 + col]) = pk.u;
        }
#pragma unroll
        for (int kc = 0; kc < 2; kc++) {
            int colp = (kc * 32 + g * 8) ^ ((r & 7) << 3);
            short8 a_pv = ld_s8(&Ps[w][r * 64 + colp]);
#pragma unroll
            for (int h7 = 0; h7 < 8; h7++) {
                int d = h7 * 16 + r;
                int colv = (kc * 32 + g * 8) ^ ((r & 7) << 3);
                short8 vf = ld_s8(&Vt[buf][d * 64 + colv]);
                acc[h7] = mfma16(a_pv, vf, acc[h7]);
            }
        }
        __syncthreads();
        buf ^= 1;
    }
    l_part += __shfl_xor(l_part, 16, 64);
    l_part += __shfl_xor(l_part, 32, 64);
    float invl[4];
#pragma unroll
    for (int reg = 0; reg < 4; reg++) invl[reg] = 1.0f / __shfl(l_part, g * 4 + reg, 64);
#pragma unroll
    for (int h7 = 0; h7 < 8; h7++)
#pragma unroll
        for (int reg = 0; reg < 4; reg++)
            attn_out[(size_t)(b * T_SEQ + qt * 16 + g * 4 + reg) * DMODEL + h * HD + h7 * 16 + r] =
                __float2bfloat16(acc[h7][reg] * invl[reg]);
}

extern "C" void kernel_launch(void* const* d_in, const int* in_sizes, int n_in,
                              void* d_out, int out_size, void* d_ws, size_t ws_size,
                              hipStream_t stream) {
    const float* x = (const float*)d_in[0];
    const int* seg = (const int*)d_in[1];
    const float* Wq = (const float*)d_in[4];
    const float* bq = (const float*)d_in[5];
    const float* Wk = (const float*)d_in[6];
    const float* bk = (const float*)d_in[7];
    const float* Wv = (const float*)d_in[8];
    const float* bv = (const float*)d_in[9];
    const float* Wo = (const float*)d_in[10];
    float* out = (float*)d_out;

    uint8_t* ws = (uint8_t*)d_ws;
    size_t off = 0;
    auto alloc = [&](size_t bytes) -> void* {
        void* p = ws + off;
        off += (bytes + 255) & ~(size_t)255;
        return p;
    };
    int* pos_ids = (int*)alloc(MROWS * sizeof(int));
    int* left_pads = (int*)alloc(16 * sizeof(int));
    __hip_bfloat16* xb = (__hip_bfloat16*)alloc((size_t)MROWS * DMODEL * 2);
    __hip_bfloat16* WqkvT = (__hip_bfloat16*)alloc((size_t)NTOT * DMODEL * 2);
    __hip_bfloat16* WoT = (__hip_bfloat16*)alloc((size_t)DMODEL * DMODEL * 2);
    __hip_bfloat16* qkv = (__hip_bfloat16*)alloc((size_t)MROWS * NTOT * 2);
    __hip_bfloat16* vbT = (__hip_bfloat16*)alloc((size_t)BATCH * KVDIM * T_SEQ * 2);
    __hip_bfloat16* attn = (__hip_bfloat16*)alloc((size_t)MROWS * DMODEL * 2);

    scan_kernel<<<BATCH, T_SEQ, 0, stream>>>(seg, pos_ids, left_pads);
    convert_bf16<<<(MROWS * DMODEL / 4 + 255) / 256, 256, 0, stream>>>(x, xb, MROWS * DMODEL);
    transpose_convert<<<dim3(DMODEL / 32, DMODEL / 32), dim3(32, 8), 0, stream>>>(Wq, WqkvT, DMODEL, DMODEL);
    transpose_convert<<<dim3(KVDIM / 32, DMODEL / 32), dim3(32, 8), 0, stream>>>(
        Wk, WqkvT + (size_t)DMODEL * DMODEL, DMODEL, KVDIM);
    transpose_convert<<<dim3(KVDIM / 32, DMODEL / 32), dim3(32, 8), 0, stream>>>(
        Wv, WqkvT + (size_t)(DMODEL + KVDIM) * DMODEL, DMODEL, KVDIM);
    transpose_convert<<<dim3(DMODEL / 32, DMODEL / 32), dim3(32, 8), 0, stream>>>(Wo, WoT, DMODEL, DMODEL);
    // exact-fill grids: 16 x 16 = 256 blocks = 1/CU
    gemmX<288, 9, 0><<<dim3(256), 9 * 64, 0, stream>>>(
        xb, WqkvT, MROWS, NTOT, DMODEL, NTOT / 288, bq, bk, bv, qkv, nullptr);
    rope_kernel<<<MROWS, 256, 0, stream>>>(qkv, pos_ids);
    transpose_v<<<dim3(KVDIM / 32, T_SEQ / 32, BATCH), dim3(32, 8), 0, stream>>>(qkv, vbT);
    attn_kernel<<<dim3(T_SEQ / 16, NKVH, BATCH), 448, 0, stream>>>(qkv, vbT, seg, left_pads, attn);
    gemmX<224, 7, 1><<<dim3(256), 7 * 64, 0, stream>>>(
        attn, WoT, MROWS, DMODEL, DMODEL, DMODEL / 224, nullptr, nullptr, nullptr, nullptr, out);
}